// Round 6
// baseline (815.073 us; speedup 1.0000x reference)
//
#include <hip/hip_runtime.h>
#include <hip/hip_bf16.h>

typedef short short8 __attribute__((ext_vector_type(8)));
typedef float f32x4 __attribute__((ext_vector_type(4)));
typedef unsigned short u16;
typedef unsigned int u32;

__device__ __forceinline__ u16 bf16rne(float f) {
    u32 u = __float_as_uint(f);
    u32 r = (u + 0x7fffu + ((u >> 16) & 1u)) >> 16;
    return (u16)r;
}
__device__ __forceinline__ float bf2f(u16 s) {
    return __uint_as_float(((u32)s) << 16);
}

// ---------------------------------------------------------------------------
// Weight swizzle into MFMA B-fragment order, bf16. For W[K x 64]:
// frag[i], i = ((nt*KT + kt)*64 + lane)*8 + j
//   = W[kt*32 + (lane>>4)*8 + j][nt*16 + (lane&15)], zero if k >= K.
// ---------------------------------------------------------------------------
__device__ __forceinline__ void swz(const float* __restrict__ src,
                                    u16* __restrict__ dst, int K, int KT,
                                    int tid0, int stride) {
    int total = 4 * KT * 512;
    for (int i = tid0; i < total; i += stride) {
        int j = i & 7, lane = (i >> 3) & 63, g = i >> 9;
        int kt = g % KT;
        int k = kt * 32 + (lane >> 4) * 8 + j;
        int n = (g / KT) * 16 + (lane & 15);
        dst[i] = (k < K) ? bf16rne(src[k * 64 + n]) : (u16)0;
    }
}

__global__ void prep_weights(
    const float* ev1, const float* ev2, const float* ec1, const float* ec2,
    const float* cg1, const float* cg2, const float* cf1, const float* cf2,
    const float* vg1, const float* vg2, const float* vf1, const float* vf2,
    const float* t1,
    u16* dev1, u16* dev2, u16* dec1, u16* dec2, u16* dcg1, u16* dcg2,
    u16* dcf1, u16* dcf2, u16* dvg1, u16* dvg2, u16* dvf1, u16* dvf2,
    u16* dt1) {
    int tid0 = blockIdx.x * blockDim.x + threadIdx.x;
    int st = gridDim.x * blockDim.x;
    swz(ev1, dev1, 19, 1, tid0, st);
    swz(ev2, dev2, 64, 2, tid0, st);
    swz(ec1, dec1, 5, 1, tid0, st);
    swz(ec2, dec2, 64, 2, tid0, st);
    swz(cg1, dcg1, 129, 5, tid0, st);
    swz(cg2, dcg2, 64, 2, tid0, st);
    swz(cf1, dcf1, 128, 4, tid0, st);
    swz(cf2, dcf2, 64, 2, tid0, st);
    swz(vg1, dvg1, 129, 5, tid0, st);
    swz(vg2, dvg2, 64, 2, tid0, st);
    swz(vf1, dvf1, 128, 4, tid0, st);
    swz(vf2, dvf2, 64, 2, tid0, st);
    swz(t1, dt1, 64, 2, tid0, st);
}

// ---------------------------------------------------------------------------
// CSR build: histogram -> hierarchical exclusive scan -> scatter => perm
// (edge ids grouped by destination node, contiguous per node).
// ---------------------------------------------------------------------------
__global__ void hist_k(const int* __restrict__ idx, int ne, u32* __restrict__ cnt) {
    for (int i = blockIdx.x * blockDim.x + threadIdx.x; i < ne;
         i += gridDim.x * blockDim.x)
        atomicAdd(&cnt[idx[i]], 1u);
}

__global__ __launch_bounds__(256) void scan_p1(const u32* __restrict__ cnt, int n,
                                               u32* __restrict__ bsum) {
    __shared__ u32 sred[256];
    int t = threadIdx.x, b = blockIdx.x;
    int i0 = b * 1024 + t * 4;
    u32 s = 0;
#pragma unroll
    for (int j = 0; j < 4; j++) { int i = i0 + j; if (i < n) s += cnt[i]; }
    sred[t] = s;
    __syncthreads();
    for (int d = 128; d > 0; d >>= 1) {
        if (t < d) sred[t] += sred[t + d];
        __syncthreads();
    }
    if (t == 0) bsum[b] = sred[0];
}

__global__ __launch_bounds__(128) void scan_p2(u32* __restrict__ bsum, int nb) {
    __shared__ u32 sc[128];
    int t = threadIdx.x;
    u32 v = (t < nb) ? bsum[t] : 0;
    u32 mine = v;
    sc[t] = v;
    __syncthreads();
    for (int d = 1; d < 128; d <<= 1) {
        u32 a = (t >= d) ? sc[t - d] : 0;
        __syncthreads();
        sc[t] += a;
        __syncthreads();
    }
    if (t < nb) bsum[t] = sc[t] - mine;   // exclusive
}

__global__ __launch_bounds__(256) void scan_p3(const u32* __restrict__ cnt, int n,
                                               const u32* __restrict__ bsum,
                                               u32* __restrict__ cur) {
    __shared__ u32 sc[256];
    int t = threadIdx.x, b = blockIdx.x;
    int i0 = b * 1024 + t * 4;
    u32 e[4];
    u32 s = 0;
#pragma unroll
    for (int j = 0; j < 4; j++) { int i = i0 + j; e[j] = (i < n) ? cnt[i] : 0; s += e[j]; }
    u32 mine = s;
    sc[t] = s;
    __syncthreads();
    for (int d = 1; d < 256; d <<= 1) {
        u32 a = (t >= d) ? sc[t - d] : 0;
        __syncthreads();
        sc[t] += a;
        __syncthreads();
    }
    u32 base = bsum[b] + sc[t] - mine;
#pragma unroll
    for (int j = 0; j < 4; j++) {
        int i = i0 + j;
        if (i < n) { cur[i] = base; base += e[j]; }
    }
}

__global__ void scatter_k(const int* __restrict__ idx, int ne,
                          u32* __restrict__ cur, int* __restrict__ perm) {
    for (int i = blockIdx.x * blockDim.x + threadIdx.x; i < ne;
         i += gridDim.x * blockDim.x) {
        u32 pos = atomicAdd(&cur[idx[i]], 1u);
        perm[pos] = i;
    }
}

// ---------------------------------------------------------------------------
// Generic MFMA layer: A[64 x KT*32] (u16, stride SA) @ Wfrag -> relu -> bf16
// into H (stride 72). Wave w owns output cols [16w, 16w+16).
// ---------------------------------------------------------------------------
template <int KT, int SA>
__device__ __forceinline__ void mfma_layer(const u16* __restrict__ Asrc,
                                           const short8* wf, float bv,
                                           u16* __restrict__ Hdst,
                                           int l15, int lq, int w) {
#pragma unroll
    for (int mt = 0; mt < 4; mt++) {
        f32x4 acc = {0.f, 0.f, 0.f, 0.f};
#pragma unroll
        for (int kt = 0; kt < KT; kt++) {
            short8 a = *(const short8*)(Asrc + (mt * 16 + l15) * SA + kt * 32 + lq * 8);
            acc = __builtin_amdgcn_mfma_f32_16x16x32_bf16(a, wf[kt], acc, 0, 0, 0);
        }
#pragma unroll
        for (int r = 0; r < 4; r++)
            Hdst[(mt * 16 + lq * 4 + r) * 72 + w * 16 + l15] =
                bf16rne(fmaxf(acc[r] + bv, 0.f));
    }
}

// ---------------------------------------------------------------------------
// Input node MLP (MFMA): x[KIN] -> 64 -> 64, relu/relu, bf16 out.
// ---------------------------------------------------------------------------
template <int KIN>
__global__ __launch_bounds__(256, 4) void node_mlp_in(
    const float* __restrict__ x, int n_nodes,
    const u16* __restrict__ w1s, const float* __restrict__ b1,
    const u16* __restrict__ w2s, const float* __restrict__ b2,
    u16* __restrict__ outbf) {
    __shared__ __align__(16) u16 A[64 * 40];
    __shared__ __align__(16) u16 H1[64 * 72];
    __shared__ __align__(16) u16 H2[64 * 72];
    int tid = threadIdx.x, l = tid & 63, w = tid >> 6;
    int l15 = l & 15, lq = l >> 4;
    int blk0 = blockIdx.x * 64;
    const int PW = 40 - KIN;
    for (int i = tid; i < 64 * PW; i += 256) {
        int r = i / PW, cc = KIN + (i - r * PW);
        A[r * 40 + cc] = 0;
    }
    for (int i = tid; i < 64 * KIN; i += 256) {
        int r = i / KIN, k = i - r * KIN;
        int gn = blk0 + r; if (gn >= n_nodes) gn = n_nodes - 1;
        A[r * 40 + k] = bf16rne(x[(size_t)gn * KIN + k]);
    }
    short8 w1f[1], w2f[2];
    w1f[0] = *(const short8*)(w1s + ((w * 1 + 0) * 64 + l) * 8);
#pragma unroll
    for (int kt = 0; kt < 2; kt++)
        w2f[kt] = *(const short8*)(w2s + ((w * 2 + kt) * 64 + l) * 8);
    float b1v = b1[w * 16 + l15], b2v = b2[w * 16 + l15];
    __syncthreads();
    mfma_layer<1, 40>(A, w1f, b1v, H1, l15, lq, w);
    __syncthreads();
    mfma_layer<2, 72>(H1, w2f, b2v, H2, l15, lq, w);
    __syncthreads();
    for (int i = tid; i < 512; i += 256) {
        int r = i >> 3, c = i & 7;
        if (blk0 + r < n_nodes)
            *(uint4*)(outbf + (size_t)(blk0 + r) * 64 + c * 8) =
                *(const uint4*)(H2 + r * 72 + c * 8);
    }
}

// ---------------------------------------------------------------------------
// f-MLP staging: A[64 x 200] bf16 = [u(64) | agg_hi(64) | agg_res(64) | pad];
// residual keeps agg ~fp32 through layer 1 (k-tiles 4,5 reuse fragments 2,3).
// ---------------------------------------------------------------------------
__device__ __forceinline__ void stage_concat_res(
    const u16* __restrict__ ubf, const float* __restrict__ agg,
    int blk0, int n_nodes, u16* __restrict__ A, int tid) {
    for (int i = tid; i < 64 * 24; i += 256) {
        int nd = i / 24, c = i - nd * 24;
        int gn = blk0 + nd; if (gn >= n_nodes) gn = n_nodes - 1;
        if (c < 8) {
            *(uint4*)(A + nd * 200 + c * 8) =
                *(const uint4*)(ubf + (size_t)gn * 64 + c * 8);
        } else {
            int q = c - 8;
            float4 av = *(const float4*)(agg + (size_t)gn * 64 + q * 4);
            u16 h0 = bf16rne(av.x), h1 = bf16rne(av.y);
            u16 h2 = bf16rne(av.z), h3 = bf16rne(av.w);
            uint2 hi;
            hi.x = (u32)h0 | ((u32)h1 << 16);
            hi.y = (u32)h2 | ((u32)h3 << 16);
            *(uint2*)(A + nd * 200 + 64 + q * 4) = hi;
            uint2 rs;
            rs.x = (u32)bf16rne(av.x - bf2f(h0)) | ((u32)bf16rne(av.y - bf2f(h1)) << 16);
            rs.y = (u32)bf16rne(av.z - bf2f(h2)) | ((u32)bf16rne(av.w - bf2f(h3)) << 16);
            *(uint2*)(A + nd * 200 + 128 + q * 4) = rs;
        }
    }
}

// ---------------------------------------------------------------------------
// c-side f-MLP (MFMA): concat(c1, agg_hi, agg_res) -> 64 -> 64, bf16 out.
// ---------------------------------------------------------------------------
__global__ __launch_bounds__(256, 2) void node_mlp_f(
    const u16* __restrict__ ubf, const float* __restrict__ agg, int n_nodes,
    const u16* __restrict__ w1s, const float* __restrict__ b1,
    const u16* __restrict__ w2s, const float* __restrict__ b2,
    u16* __restrict__ outbf) {
    __shared__ __align__(16) u16 A[64 * 200];
    __shared__ __align__(16) u16 H1[64 * 72];
    int tid = threadIdx.x, l = tid & 63, w = tid >> 6;
    int l15 = l & 15, lq = l >> 4;
    int blk0 = blockIdx.x * 64;
    stage_concat_res(ubf, agg, blk0, n_nodes, A, tid);
    short8 w1f[6], w2f[2];
#pragma unroll
    for (int kt = 0; kt < 4; kt++)
        w1f[kt] = *(const short8*)(w1s + ((w * 4 + kt) * 64 + l) * 8);
    w1f[4] = w1f[2];
    w1f[5] = w1f[3];
#pragma unroll
    for (int kt = 0; kt < 2; kt++)
        w2f[kt] = *(const short8*)(w2s + ((w * 2 + kt) * 64 + l) * 8);
    float b1v = b1[w * 16 + l15], b2v = b2[w * 16 + l15];
    __syncthreads();
    mfma_layer<6, 200>(A, w1f, b1v, H1, l15, lq, w);
    __syncthreads();
    mfma_layer<2, 72>(H1, w2f, b2v, A, l15, lq, w);
    __syncthreads();
    for (int i = tid; i < 512; i += 256) {
        int r = i >> 3, c = i & 7;
        if (blk0 + r < n_nodes)
            *(uint4*)(outbf + (size_t)(blk0 + r) * 64 + c * 8) =
                *(const uint4*)(A + r * 72 + c * 8);
    }
}

// ---------------------------------------------------------------------------
// v-side f-MLP + tail (MFMA).
// ---------------------------------------------------------------------------
__global__ __launch_bounds__(256, 2) void node_mlp_vf_tail(
    const u16* __restrict__ vbf, const float* __restrict__ agg, int n_nodes,
    const u16* __restrict__ w1s, const float* __restrict__ b1,
    const u16* __restrict__ w2s, const float* __restrict__ b2,
    const u16* __restrict__ t1s, const float* __restrict__ tb1,
    const float* __restrict__ tw2, const float* __restrict__ tb2,
    float* __restrict__ out) {
    __shared__ __align__(16) char smem[64 * 200 * 2 + 2 * 64 * 72 * 2];
    u16* A = (u16*)smem;
    float* XF = (float*)smem;       // stride 65, reuses A region
    u16* H1 = (u16*)(smem + 25600);
    u16* H2 = (u16*)(smem + 25600 + 9216);
    int tid = threadIdx.x, l = tid & 63, w = tid >> 6;
    int l15 = l & 15, lq = l >> 4;
    int blk0 = blockIdx.x * 64;
    stage_concat_res(vbf, agg, blk0, n_nodes, A, tid);
    short8 w1f[6], w2f[2], t1f[2];
#pragma unroll
    for (int kt = 0; kt < 4; kt++)
        w1f[kt] = *(const short8*)(w1s + ((w * 4 + kt) * 64 + l) * 8);
    w1f[4] = w1f[2];
    w1f[5] = w1f[3];
#pragma unroll
    for (int kt = 0; kt < 2; kt++) {
        w2f[kt] = *(const short8*)(w2s + ((w * 2 + kt) * 64 + l) * 8);
        t1f[kt] = *(const short8*)(t1s + ((w * 2 + kt) * 64 + l) * 8);
    }
    float b1v = b1[w * 16 + l15], b2v = b2[w * 16 + l15];
    float tb1v = tb1[w * 16 + l15];
    __syncthreads();
    mfma_layer<6, 200>(A, w1f, b1v, H1, l15, lq, w);
    __syncthreads();
    mfma_layer<2, 72>(H1, w2f, b2v, H2, l15, lq, w);
    __syncthreads();
#pragma unroll
    for (int mt = 0; mt < 4; mt++) {
        f32x4 acc = {0.f, 0.f, 0.f, 0.f};
#pragma unroll
        for (int kt = 0; kt < 2; kt++) {
            short8 a = *(const short8*)(H2 + (mt * 16 + l15) * 72 + kt * 32 + lq * 8);
            acc = __builtin_amdgcn_mfma_f32_16x16x32_bf16(a, t1f[kt], acc, 0, 0, 0);
        }
#pragma unroll
        for (int r = 0; r < 4; r++)
            XF[(mt * 16 + lq * 4 + r) * 65 + w * 16 + l15] =
                fmaxf(acc[r] + tb1v, 0.f);
    }
    __syncthreads();
    float s0 = tb2[2 * w], s1 = tb2[2 * w + 1];
    for (int k = 0; k < 64; k++) {
        float xk = XF[l * 65 + k];
        float2 wp = *(const float2*)(tw2 + k * 8 + 2 * w);
        s0 = fmaf(xk, wp.x, s0);
        s1 = fmaf(xk, wp.y, s1);
    }
    if (blk0 + l < n_nodes) {
        float2 r;
        r.x = 1.f / (1.f + __expf(-s0));
        r.y = 1.f / (1.f + __expf(-s1));
        *(float2*)(out + (size_t)(blk0 + l) * 8 + 2 * w) = r;
    }
}

// ---------------------------------------------------------------------------
// Edge conv over SORTED edge order (perm groups edges by u). Epilogue:
// layer-2 output to f32 LDS, per-lane 16-row segmented scan, one atomic per
// run boundary (~8x fewer atomics than per-element). 3 barriers/tile.
// ---------------------------------------------------------------------------
#define AROW 168
#define HROW 72

__global__ __launch_bounds__(256, 4) void edge_conv(
    const u16* __restrict__ u_feat, const u16* __restrict__ v_feat,
    const int* __restrict__ u_idx, const int* __restrict__ v_idx,
    const float* __restrict__ e_val, const int* __restrict__ perm,
    const u16* __restrict__ w1s, const u16* __restrict__ w2s,
    const float* __restrict__ b1, const float* __restrict__ b2,
    float* __restrict__ agg, int n_tiles) {
    __shared__ __align__(16) u16 A[64 * AROW];
    __shared__ __align__(16) u16 Hs[64 * HROW];
    __shared__ __align__(16) float Gs[64 * 65];
    __shared__ int Su[2][64];

    int tid = threadIdx.x;
    int lane = tid & 63;
    int w = tid >> 6;
    int l15 = lane & 15, lq = lane >> 4;
    int cch = tid & 15, e0 = tid >> 4;

    for (int i = tid; i < 64 * (AROW - 129); i += 256) {
        int r = i / (AROW - 129);
        int cc = 129 + (i - r * (AROW - 129));
        A[r * AROW + cc] = 0;
    }

    short8 w1f[5], w2f[2];
#pragma unroll
    for (int kt = 0; kt < 5; kt++)
        w1f[kt] = *(const short8*)(w1s + ((w * 5 + kt) * 64 + lane) * 8);
#pragma unroll
    for (int kt = 0; kt < 2; kt++)
        w2f[kt] = *(const short8*)(w2s + ((w * 2 + kt) * 64 + lane) * 8);
    float b1v = b1[w * 16 + l15];
    float b2v = b2[w * 16 + l15];

    const int gcol = (cch < 8) ? cch * 8 : 64 + (cch - 8) * 8;
    const int col = w * 16 + l15;
    int par = 0;
    __syncthreads();

    for (int tile = blockIdx.x; tile < n_tiles; tile += gridDim.x) {
        // ---- gather (sorted order via perm) ----
#pragma unroll
        for (int t = 0; t < 4; t++) {
            int e = e0 + t * 16;
            int ge = tile * 64 + e;
            int p = perm[ge];
            const u16* src = (cch < 8)
                ? (u_feat + (size_t)u_idx[p] * 64 + cch * 8)
                : (v_feat + (size_t)v_idx[p] * 64 + (cch - 8) * 8);
            *(uint4*)(&A[e * AROW + gcol]) = *(const uint4*)src;
            if (cch == 0) A[e * AROW + 128] = bf16rne(e_val[p]);
        }
        if (tid < 64) Su[par][tid] = u_idx[perm[tile * 64 + tid]];
        __syncthreads();

        // ---- layer 1 ----
#pragma unroll
        for (int mt = 0; mt < 4; mt++) {
            short8 a1[5];
#pragma unroll
            for (int kt = 0; kt < 5; kt++)
                a1[kt] = *(const short8*)(&A[(mt * 16 + l15) * AROW + kt * 32 + lq * 8]);
            f32x4 acc = {0.f, 0.f, 0.f, 0.f};
#pragma unroll
            for (int kt = 0; kt < 5; kt++)
                acc = __builtin_amdgcn_mfma_f32_16x16x32_bf16(a1[kt], w1f[kt], acc, 0, 0, 0);
#pragma unroll
            for (int r = 0; r < 4; r++) {
                float hv = fmaxf(acc[r] + b1v, 0.f);
                Hs[(mt * 16 + lq * 4 + r) * HROW + w * 16 + l15] = bf16rne(hv);
            }
        }
        __syncthreads();

        // ---- layer 2 -> f32 LDS ----
#pragma unroll
        for (int mt = 0; mt < 4; mt++) {
            short8 a2[2];
#pragma unroll
            for (int kt = 0; kt < 2; kt++)
                a2[kt] = *(const short8*)(&Hs[(mt * 16 + l15) * HROW + kt * 32 + lq * 8]);
            f32x4 acc = {0.f, 0.f, 0.f, 0.f};
#pragma unroll
            for (int kt = 0; kt < 2; kt++)
                acc = __builtin_amdgcn_mfma_f32_16x16x32_bf16(a2[kt], w2f[kt], acc, 0, 0, 0);
#pragma unroll
            for (int r = 0; r < 4; r++)
                Gs[(mt * 16 + lq * 4 + r) * 65 + col] = fmaxf(acc[r] + b2v, 0.f);
        }
        __syncthreads();

        // ---- segmented reduce: lane scans rows [16lq,16lq+16) for its col ----
        {
            int base = lq * 16;
            float partial = 0.f;
            int cur = Su[par][base];
#pragma unroll
            for (int s = 0; s < 16; s++) {
                partial += Gs[(base + s) * 65 + col];
                int nxt = (s == 15) ? -1 : Su[par][base + s + 1];
                if (nxt != cur) {
                    __hip_atomic_fetch_add(&agg[(size_t)cur * 64 + col], partial,
                                           __ATOMIC_RELAXED, __HIP_MEMORY_SCOPE_AGENT);
                    partial = 0.f;
                    cur = nxt;
                }
            }
        }
        par ^= 1;
        // no barrier: next gather writes A / Su[par^1]; Gs protected by the
        // barrier chain before next layer-2.
    }
}

extern "C" void kernel_launch(void* const* d_in, const int* in_sizes, int n_in,
                              void* d_out, int out_size, void* d_ws, size_t ws_size,
                              hipStream_t stream) {
    const float* v        = (const float*)d_in[0];
    const float* c        = (const float*)d_in[1];
    const int*   cons_idx = (const int*)d_in[2];
    const int*   var_idx  = (const int*)d_in[3];
    const float* e_val    = (const float*)d_in[4];
    const float* ev_w1 = (const float*)d_in[5],  *ev_b1 = (const float*)d_in[6];
    const float* ev_w2 = (const float*)d_in[7],  *ev_b2 = (const float*)d_in[8];
    const float* ec_w1 = (const float*)d_in[9],  *ec_b1 = (const float*)d_in[10];
    const float* ec_w2 = (const float*)d_in[11], *ec_b2 = (const float*)d_in[12];
    const float* cg_w1 = (const float*)d_in[13], *cg_b1 = (const float*)d_in[14];
    const float* cg_w2 = (const float*)d_in[15], *cg_b2 = (const float*)d_in[16];
    const float* cf_w1 = (const float*)d_in[17], *cf_b1 = (const float*)d_in[18];
    const float* cf_w2 = (const float*)d_in[19], *cf_b2 = (const float*)d_in[20];
    const float* vg_w1 = (const float*)d_in[21], *vg_b1 = (const float*)d_in[22];
    const float* vg_w2 = (const float*)d_in[23], *vg_b2 = (const float*)d_in[24];
    const float* vf_w1 = (const float*)d_in[25], *vf_b1 = (const float*)d_in[26];
    const float* vf_w2 = (const float*)d_in[27], *vf_b2 = (const float*)d_in[28];
    const float* t_w1  = (const float*)d_in[29], *t_b1  = (const float*)d_in[30];
    const float* t_w2  = (const float*)d_in[31], *t_b2  = (const float*)d_in[32];

    const int NV = in_sizes[0] / 19;
    const int NC = in_sizes[1] / 5;
    const int NE = in_sizes[4];

    char* ws = (char*)d_ws;
    size_t off = 0;
    u16* v1bf = (u16*)(ws + off); off += (size_t)NV * 64 * 2;
    u16* c1bf = (u16*)(ws + off); off += (size_t)NC * 64 * 2;
    u16* c2bf = (u16*)(ws + off); off += (size_t)NC * 64 * 2;
    float* agg_c = (float*)(ws + off); off += (size_t)NC * 64 * 4;
    float* agg_v = (float*)(ws + off); off += (size_t)NV * 64 * 4;
    u16* ev1s = (u16*)(ws + off); off += 2048 * 2;
    u16* ev2s = (u16*)(ws + off); off += 4096 * 2;
    u16* ec1s = (u16*)(ws + off); off += 2048 * 2;
    u16* ec2s = (u16*)(ws + off); off += 4096 * 2;
    u16* cg1s = (u16*)(ws + off); off += 10240 * 2;
    u16* cg2s = (u16*)(ws + off); off += 4096 * 2;
    u16* cf1s = (u16*)(ws + off); off += 8192 * 2;
    u16* cf2s = (u16*)(ws + off); off += 4096 * 2;
    u16* vg1s = (u16*)(ws + off); off += 10240 * 2;
    u16* vg2s = (u16*)(ws + off); off += 4096 * 2;
    u16* vf1s = (u16*)(ws + off); off += 8192 * 2;
    u16* vf2s = (u16*)(ws + off); off += 4096 * 2;
    u16* t1s  = (u16*)(ws + off); off += 4096 * 2;
    off = (off + 255) & ~(size_t)255;
    u32* cnt_c  = (u32*)(ws + off); off += (size_t)NC * 4;
    u32* cur_c  = (u32*)(ws + off); off += (size_t)NC * 4;
    u32* bsum_c = (u32*)(ws + off); off += 128 * 4;
    int* perm_c = (int*)(ws + off); off += (size_t)NE * 4;
    u32* cnt_v  = (u32*)(ws + off); off += (size_t)NV * 4;
    u32* cur_v  = (u32*)(ws + off); off += (size_t)NV * 4;
    u32* bsum_v = (u32*)(ws + off); off += 128 * 4;
    int* perm_v = (int*)(ws + off); off += (size_t)NE * 4;

    const int nb_c = (NC + 1023) / 1024;
    const int nb_v = (NV + 1023) / 1024;

    // --- CSR builds (independent of everything else) ---
    hipMemsetAsync(cnt_c, 0, (size_t)NC * 4, stream);
    hipMemsetAsync(cnt_v, 0, (size_t)NV * 4, stream);
    hist_k<<<2048, 256, 0, stream>>>(cons_idx, NE, cnt_c);
    hist_k<<<2048, 256, 0, stream>>>(var_idx, NE, cnt_v);
    scan_p1<<<nb_c, 256, 0, stream>>>(cnt_c, NC, bsum_c);
    scan_p2<<<1, 128, 0, stream>>>(bsum_c, nb_c);
    scan_p3<<<nb_c, 256, 0, stream>>>(cnt_c, NC, bsum_c, cur_c);
    scatter_k<<<2048, 256, 0, stream>>>(cons_idx, NE, cur_c, perm_c);
    scan_p1<<<nb_v, 256, 0, stream>>>(cnt_v, NV, bsum_v);
    scan_p2<<<1, 128, 0, stream>>>(bsum_v, nb_v);
    scan_p3<<<nb_v, 256, 0, stream>>>(cnt_v, NV, bsum_v, cur_v);
    scatter_k<<<2048, 256, 0, stream>>>(var_idx, NE, cur_v, perm_v);

    prep_weights<<<40, 256, 0, stream>>>(
        ev_w1, ev_w2, ec_w1, ec_w2, cg_w1, cg_w2, cf_w1, cf_w2,
        vg_w1, vg_w2, vf_w1, vf_w2, t_w1,
        ev1s, ev2s, ec1s, ec2s, cg1s, cg2s, cf1s, cf2s,
        vg1s, vg2s, vf1s, vf2s, t1s);

    node_mlp_in<19><<<(NV + 63) / 64, 256, 0, stream>>>(
        v, NV, ev1s, ev_b1, ev2s, ev_b2, v1bf);
    node_mlp_in<5><<<(NC + 63) / 64, 256, 0, stream>>>(
        c, NC, ec1s, ec_b1, ec2s, ec_b2, c1bf);

    hipMemsetAsync(agg_c, 0, (size_t)NC * 64 * 4, stream);
    edge_conv<<<768, 256, 0, stream>>>(c1bf, v1bf, cons_idx, var_idx, e_val,
                                       perm_c, cg1s, cg2s, cg_b1, cg_b2,
                                       agg_c, NE / 64);
    node_mlp_f<<<(NC + 63) / 64, 256, 0, stream>>>(
        c1bf, agg_c, NC, cf1s, cf_b1, cf2s, cf_b2, c2bf);

    hipMemsetAsync(agg_v, 0, (size_t)NV * 64 * 4, stream);
    edge_conv<<<768, 256, 0, stream>>>(v1bf, c2bf, var_idx, cons_idx, e_val,
                                       perm_v, vg1s, vg2s, vg_b1, vg_b2,
                                       agg_v, NE / 64);
    node_mlp_vf_tail<<<(NV + 63) / 64, 256, 0, stream>>>(
        v1bf, agg_v, NV, vf1s, vf_b1, vf2s, vf_b2,
        t1s, t_b1, t_w2, t_b2, (float*)d_out);
}

// Round 7
// 667.995 us; speedup vs baseline: 1.2202x; 1.2202x over previous
//
#include <hip/hip_runtime.h>
#include <hip/hip_bf16.h>

typedef short short8 __attribute__((ext_vector_type(8)));
typedef float f32x4 __attribute__((ext_vector_type(4)));
typedef unsigned short u16;
typedef unsigned int u32;

__device__ __forceinline__ u16 bf16rne(float f) {
    u32 u = __float_as_uint(f);
    u32 r = (u + 0x7fffu + ((u >> 16) & 1u)) >> 16;
    return (u16)r;
}
__device__ __forceinline__ float bf2f(u16 s) {
    return __uint_as_float(((u32)s) << 16);
}

// ---------------------------------------------------------------------------
// Weight swizzle into MFMA B-fragment order, bf16 (K <= KT*32, zero-padded).
// ---------------------------------------------------------------------------
__device__ __forceinline__ void swz(const float* __restrict__ src,
                                    u16* __restrict__ dst, int K, int KT,
                                    int tid0, int stride) {
    int total = 4 * KT * 512;
    for (int i = tid0; i < total; i += stride) {
        int j = i & 7, lane = (i >> 3) & 63, g = i >> 9;
        int kt = g % KT;
        int k = kt * 32 + (lane >> 4) * 8 + j;
        int n = (g / KT) * 16 + (lane & 15);
        dst[i] = (k < K) ? bf16rne(src[k * 64 + n]) : (u16)0;
    }
}

__global__ void prep_weights(
    const float* ev1, const float* ev2, const float* ec1, const float* ec2,
    const float* cg1, const float* cg2, const float* cf1, const float* cf2,
    const float* vg1, const float* vg2, const float* vf1, const float* vf2,
    const float* t1,
    u16* dev1, u16* dev2, u16* dec1, u16* dec2, u16* dcg1, u16* dcg2,
    u16* dcf1, u16* dcf2, u16* dvg1, u16* dvg2, u16* dvf1, u16* dvf2,
    u16* dt1) {
    int tid0 = blockIdx.x * blockDim.x + threadIdx.x;
    int st = gridDim.x * blockDim.x;
    swz(ev1, dev1, 19, 1, tid0, st);
    swz(ev2, dev2, 64, 2, tid0, st);
    swz(ec1, dec1, 5, 1, tid0, st);
    swz(ec2, dec2, 64, 2, tid0, st);
    swz(cg1, dcg1, 128, 4, tid0, st);   // row 128 (e_val) handled in epilogue
    swz(cg2, dcg2, 64, 2, tid0, st);
    swz(cf1, dcf1, 128, 4, tid0, st);
    swz(cf2, dcf2, 64, 2, tid0, st);
    swz(vg1, dvg1, 128, 4, tid0, st);
    swz(vg2, dvg2, 64, 2, tid0, st);
    swz(vf1, dvf1, 128, 4, tid0, st);
    swz(vf2, dvf2, 64, 2, tid0, st);
    swz(t1, dt1, 64, 2, tid0, st);
}

// ---------------------------------------------------------------------------
// CSR build, merged: hist both sides -> 2D scans -> scatter sorted payloads
// directly (no perm array, no second gather pass).
// ---------------------------------------------------------------------------
__global__ void hist_both(const int* __restrict__ ci, const int* __restrict__ vi,
                          int ne, u32* __restrict__ cc, u32* __restrict__ cv) {
    for (int i = blockIdx.x * blockDim.x + threadIdx.x; i < ne;
         i += gridDim.x * blockDim.x) {
        atomicAdd(&cc[ci[i]], 1u);
        atomicAdd(&cv[vi[i]], 1u);
    }
}

__global__ __launch_bounds__(256) void scan_p1(
    const u32* __restrict__ c0, int n0, u32* __restrict__ bs0,
    const u32* __restrict__ c1, int n1, u32* __restrict__ bs1) {
    const u32* cnt = blockIdx.y ? c1 : c0;
    int n = blockIdx.y ? n1 : n0;
    u32* bsum = blockIdx.y ? bs1 : bs0;
    int nb = (n + 1023) / 1024;
    int b = blockIdx.x;
    if (b >= nb) return;
    __shared__ u32 sred[256];
    int t = threadIdx.x;
    int i0 = b * 1024 + t * 4;
    u32 s = 0;
#pragma unroll
    for (int j = 0; j < 4; j++) { int i = i0 + j; if (i < n) s += cnt[i]; }
    sred[t] = s;
    __syncthreads();
    for (int d = 128; d > 0; d >>= 1) {
        if (t < d) sred[t] += sred[t + d];
        __syncthreads();
    }
    if (t == 0) bsum[b] = sred[0];
}

__global__ __launch_bounds__(128) void scan_p2(u32* __restrict__ bs0, int n0,
                                               u32* __restrict__ bs1, int n1) {
    u32* bsum = blockIdx.y ? bs1 : bs0;
    int nb = ((blockIdx.y ? n1 : n0) + 1023) / 1024;
    __shared__ u32 sc[128];
    int t = threadIdx.x;
    u32 v = (t < nb) ? bsum[t] : 0;
    u32 mine = v;
    sc[t] = v;
    __syncthreads();
    for (int d = 1; d < 128; d <<= 1) {
        u32 a = (t >= d) ? sc[t - d] : 0;
        __syncthreads();
        sc[t] += a;
        __syncthreads();
    }
    if (t < nb) bsum[t] = sc[t] - mine;   // exclusive
}

__global__ __launch_bounds__(256) void scan_p3(
    const u32* __restrict__ c0, int n0, const u32* __restrict__ bs0,
    u32* __restrict__ cu0,
    const u32* __restrict__ c1, int n1, const u32* __restrict__ bs1,
    u32* __restrict__ cu1) {
    const u32* cnt = blockIdx.y ? c1 : c0;
    int n = blockIdx.y ? n1 : n0;
    const u32* bsum = blockIdx.y ? bs1 : bs0;
    u32* cur = blockIdx.y ? cu1 : cu0;
    int nb = (n + 1023) / 1024;
    int b = blockIdx.x;
    if (b >= nb) return;
    __shared__ u32 sc[256];
    int t = threadIdx.x;
    int i0 = b * 1024 + t * 4;
    u32 e[4];
    u32 s = 0;
#pragma unroll
    for (int j = 0; j < 4; j++) { int i = i0 + j; e[j] = (i < n) ? cnt[i] : 0; s += e[j]; }
    u32 mine = s;
    sc[t] = s;
    __syncthreads();
    for (int d = 1; d < 256; d <<= 1) {
        u32 a = (t >= d) ? sc[t - d] : 0;
        __syncthreads();
        sc[t] += a;
        __syncthreads();
    }
    u32 base = bsum[b] + sc[t] - mine;
#pragma unroll
    for (int j = 0; j < 4; j++) {
        int i = i0 + j;
        if (i < n) { cur[i] = base; base += e[j]; }
    }
}

__global__ void scatter_both(const int* __restrict__ ci, const int* __restrict__ vi,
                             const float* __restrict__ ev, int ne,
                             u32* __restrict__ cur_c, u32* __restrict__ cur_v,
                             int2* __restrict__ se_c_uv, float* __restrict__ se_c_ev,
                             int2* __restrict__ se_v_uv, float* __restrict__ se_v_ev) {
    for (int i = blockIdx.x * blockDim.x + threadIdx.x; i < ne;
         i += gridDim.x * blockDim.x) {
        int cI = ci[i], vI = vi[i];
        float e = ev[i];
        u32 pc = atomicAdd(&cur_c[cI], 1u);
        se_c_uv[pc] = make_int2(cI, vI);
        se_c_ev[pc] = e;
        u32 pv = atomicAdd(&cur_v[vI], 1u);
        se_v_uv[pv] = make_int2(vI, cI);
        se_v_ev[pv] = e;
    }
}

// ---------------------------------------------------------------------------
// Generic MFMA layer for node MLPs (stride-72 bf16 out).
// ---------------------------------------------------------------------------
template <int KT, int SA>
__device__ __forceinline__ void mfma_layer(const u16* __restrict__ Asrc,
                                           const short8* wf, float bv,
                                           u16* __restrict__ Hdst,
                                           int l15, int lq, int w) {
#pragma unroll
    for (int mt = 0; mt < 4; mt++) {
        f32x4 acc = {0.f, 0.f, 0.f, 0.f};
#pragma unroll
        for (int kt = 0; kt < KT; kt++) {
            short8 a = *(const short8*)(Asrc + (mt * 16 + l15) * SA + kt * 32 + lq * 8);
            acc = __builtin_amdgcn_mfma_f32_16x16x32_bf16(a, wf[kt], acc, 0, 0, 0);
        }
#pragma unroll
        for (int r = 0; r < 4; r++)
            Hdst[(mt * 16 + lq * 4 + r) * 72 + w * 16 + l15] =
                bf16rne(fmaxf(acc[r] + bv, 0.f));
    }
}

// ---------------------------------------------------------------------------
// Input node MLP (MFMA): x[KIN] -> 64 -> 64, relu/relu, bf16 out.
// ---------------------------------------------------------------------------
template <int KIN>
__global__ __launch_bounds__(256, 4) void node_mlp_in(
    const float* __restrict__ x, int n_nodes,
    const u16* __restrict__ w1s, const float* __restrict__ b1,
    const u16* __restrict__ w2s, const float* __restrict__ b2,
    u16* __restrict__ outbf) {
    __shared__ __align__(16) u16 A[64 * 40];
    __shared__ __align__(16) u16 H1[64 * 72];
    __shared__ __align__(16) u16 H2[64 * 72];
    int tid = threadIdx.x, l = tid & 63, w = tid >> 6;
    int l15 = l & 15, lq = l >> 4;
    int blk0 = blockIdx.x * 64;
    const int PW = 40 - KIN;
    for (int i = tid; i < 64 * PW; i += 256) {
        int r = i / PW, cc = KIN + (i - r * PW);
        A[r * 40 + cc] = 0;
    }
    for (int i = tid; i < 64 * KIN; i += 256) {
        int r = i / KIN, k = i - r * KIN;
        int gn = blk0 + r; if (gn >= n_nodes) gn = n_nodes - 1;
        A[r * 40 + k] = bf16rne(x[(size_t)gn * KIN + k]);
    }
    short8 w1f[1], w2f[2];
    w1f[0] = *(const short8*)(w1s + ((w * 1 + 0) * 64 + l) * 8);
#pragma unroll
    for (int kt = 0; kt < 2; kt++)
        w2f[kt] = *(const short8*)(w2s + ((w * 2 + kt) * 64 + l) * 8);
    float b1v = b1[w * 16 + l15], b2v = b2[w * 16 + l15];
    __syncthreads();
    mfma_layer<1, 40>(A, w1f, b1v, H1, l15, lq, w);
    __syncthreads();
    mfma_layer<2, 72>(H1, w2f, b2v, H2, l15, lq, w);
    __syncthreads();
    for (int i = tid; i < 512; i += 256) {
        int r = i >> 3, c = i & 7;
        if (blk0 + r < n_nodes)
            *(uint4*)(outbf + (size_t)(blk0 + r) * 64 + c * 8) =
                *(const uint4*)(H2 + r * 72 + c * 8);
    }
}

// ---------------------------------------------------------------------------
// f-MLP staging: A[64 x 200] bf16 = [u(64) | agg_hi(64) | agg_res(64) | pad].
// ---------------------------------------------------------------------------
__device__ __forceinline__ void stage_concat_res(
    const u16* __restrict__ ubf, const float* __restrict__ agg,
    int blk0, int n_nodes, u16* __restrict__ A, int tid) {
    for (int i = tid; i < 64 * 24; i += 256) {
        int nd = i / 24, c = i - nd * 24;
        int gn = blk0 + nd; if (gn >= n_nodes) gn = n_nodes - 1;
        if (c < 8) {
            *(uint4*)(A + nd * 200 + c * 8) =
                *(const uint4*)(ubf + (size_t)gn * 64 + c * 8);
        } else {
            int q = c - 8;
            float4 av = *(const float4*)(agg + (size_t)gn * 64 + q * 4);
            u16 h0 = bf16rne(av.x), h1 = bf16rne(av.y);
            u16 h2 = bf16rne(av.z), h3 = bf16rne(av.w);
            uint2 hi;
            hi.x = (u32)h0 | ((u32)h1 << 16);
            hi.y = (u32)h2 | ((u32)h3 << 16);
            *(uint2*)(A + nd * 200 + 64 + q * 4) = hi;
            uint2 rs;
            rs.x = (u32)bf16rne(av.x - bf2f(h0)) | ((u32)bf16rne(av.y - bf2f(h1)) << 16);
            rs.y = (u32)bf16rne(av.z - bf2f(h2)) | ((u32)bf16rne(av.w - bf2f(h3)) << 16);
            *(uint2*)(A + nd * 200 + 128 + q * 4) = rs;
        }
    }
}

// ---------------------------------------------------------------------------
// c-side f-MLP (MFMA).
// ---------------------------------------------------------------------------
__global__ __launch_bounds__(256, 2) void node_mlp_f(
    const u16* __restrict__ ubf, const float* __restrict__ agg, int n_nodes,
    const u16* __restrict__ w1s, const float* __restrict__ b1,
    const u16* __restrict__ w2s, const float* __restrict__ b2,
    u16* __restrict__ outbf) {
    __shared__ __align__(16) u16 A[64 * 200];
    __shared__ __align__(16) u16 H1[64 * 72];
    int tid = threadIdx.x, l = tid & 63, w = tid >> 6;
    int l15 = l & 15, lq = l >> 4;
    int blk0 = blockIdx.x * 64;
    stage_concat_res(ubf, agg, blk0, n_nodes, A, tid);
    short8 w1f[6], w2f[2];
#pragma unroll
    for (int kt = 0; kt < 4; kt++)
        w1f[kt] = *(const short8*)(w1s + ((w * 4 + kt) * 64 + l) * 8);
    w1f[4] = w1f[2];
    w1f[5] = w1f[3];
#pragma unroll
    for (int kt = 0; kt < 2; kt++)
        w2f[kt] = *(const short8*)(w2s + ((w * 2 + kt) * 64 + l) * 8);
    float b1v = b1[w * 16 + l15], b2v = b2[w * 16 + l15];
    __syncthreads();
    mfma_layer<6, 200>(A, w1f, b1v, H1, l15, lq, w);
    __syncthreads();
    mfma_layer<2, 72>(H1, w2f, b2v, A, l15, lq, w);
    __syncthreads();
    for (int i = tid; i < 512; i += 256) {
        int r = i >> 3, c = i & 7;
        if (blk0 + r < n_nodes)
            *(uint4*)(outbf + (size_t)(blk0 + r) * 64 + c * 8) =
                *(const uint4*)(A + r * 72 + c * 8);
    }
}

// ---------------------------------------------------------------------------
// v-side f-MLP + tail (MFMA).
// ---------------------------------------------------------------------------
__global__ __launch_bounds__(256, 2) void node_mlp_vf_tail(
    const u16* __restrict__ vbf, const float* __restrict__ agg, int n_nodes,
    const u16* __restrict__ w1s, const float* __restrict__ b1,
    const u16* __restrict__ w2s, const float* __restrict__ b2,
    const u16* __restrict__ t1s, const float* __restrict__ tb1,
    const float* __restrict__ tw2, const float* __restrict__ tb2,
    float* __restrict__ out) {
    __shared__ __align__(16) char smem[64 * 200 * 2 + 2 * 64 * 72 * 2];
    u16* A = (u16*)smem;
    float* XF = (float*)smem;       // stride 65, reuses A region
    u16* H1 = (u16*)(smem + 25600);
    u16* H2 = (u16*)(smem + 25600 + 9216);
    int tid = threadIdx.x, l = tid & 63, w = tid >> 6;
    int l15 = l & 15, lq = l >> 4;
    int blk0 = blockIdx.x * 64;
    stage_concat_res(vbf, agg, blk0, n_nodes, A, tid);
    short8 w1f[6], w2f[2], t1f[2];
#pragma unroll
    for (int kt = 0; kt < 4; kt++)
        w1f[kt] = *(const short8*)(w1s + ((w * 4 + kt) * 64 + l) * 8);
    w1f[4] = w1f[2];
    w1f[5] = w1f[3];
#pragma unroll
    for (int kt = 0; kt < 2; kt++) {
        w2f[kt] = *(const short8*)(w2s + ((w * 2 + kt) * 64 + l) * 8);
        t1f[kt] = *(const short8*)(t1s + ((w * 2 + kt) * 64 + l) * 8);
    }
    float b1v = b1[w * 16 + l15], b2v = b2[w * 16 + l15];
    float tb1v = tb1[w * 16 + l15];
    __syncthreads();
    mfma_layer<6, 200>(A, w1f, b1v, H1, l15, lq, w);
    __syncthreads();
    mfma_layer<2, 72>(H1, w2f, b2v, H2, l15, lq, w);
    __syncthreads();
#pragma unroll
    for (int mt = 0; mt < 4; mt++) {
        f32x4 acc = {0.f, 0.f, 0.f, 0.f};
#pragma unroll
        for (int kt = 0; kt < 2; kt++) {
            short8 a = *(const short8*)(H2 + (mt * 16 + l15) * 72 + kt * 32 + lq * 8);
            acc = __builtin_amdgcn_mfma_f32_16x16x32_bf16(a, t1f[kt], acc, 0, 0, 0);
        }
#pragma unroll
        for (int r = 0; r < 4; r++)
            XF[(mt * 16 + lq * 4 + r) * 65 + w * 16 + l15] =
                fmaxf(acc[r] + tb1v, 0.f);
    }
    __syncthreads();
    float s0 = tb2[2 * w], s1 = tb2[2 * w + 1];
    for (int k = 0; k < 64; k++) {
        float xk = XF[l * 65 + k];
        float2 wp = *(const float2*)(tw2 + k * 8 + 2 * w);
        s0 = fmaf(xk, wp.x, s0);
        s1 = fmaf(xk, wp.y, s1);
    }
    if (blk0 + l < n_nodes) {
        float2 r;
        r.x = 1.f / (1.f + __expf(-s0));
        r.y = 1.f / (1.f + __expf(-s1));
        *(float2*)(out + (size_t)(blk0 + l) * 8 + 2 * w) = r;
    }
}

// ---------------------------------------------------------------------------
// Edge conv v3: sorted payload arrays (coalesced), e_val folded into the L1
// epilogue (fp32, frees K-tile 5 and all pad columns), Gs aliased onto dead
// A region. LDS 26.5 KB -> 6 blocks/CU. 4 barriers/tile.
//   A:  bf16 [64 x 128], stride 136 u16 (17408 B)  } union (Gs fits in A)
//   Gs: f32  [64 x 64],  stride 67 f32  (17152 B)  }
//   Hs: bf16 [64 x 64],  stride 72 u16  (9216 B)
//   Su/Sev: 64 x int / f32 (512 B)
// ---------------------------------------------------------------------------
__global__ __launch_bounds__(256, 6) void edge_conv(
    const u16* __restrict__ u_feat, const u16* __restrict__ v_feat,
    const int2* __restrict__ se_uv, const float* __restrict__ se_ev,
    const u16* __restrict__ w1s, const float* __restrict__ w1last,
    const u16* __restrict__ w2s,
    const float* __restrict__ b1, const float* __restrict__ b2,
    float* __restrict__ agg, int n_tiles) {
    __shared__ __align__(16) char smem[27136];
    u16* A = (u16*)smem;                   // stride 136
    float* Gs = (float*)smem;              // stride 67, aliases A
    u16* Hs = (u16*)(smem + 17408);        // stride 72
    int* Su = (int*)(smem + 26624);
    float* Sev = (float*)(smem + 26880);

    int tid = threadIdx.x;
    int lane = tid & 63;
    int w = tid >> 6;
    int l15 = lane & 15, lq = lane >> 4;
    int cch = tid & 15, e0 = tid >> 4;

    short8 w1f[4], w2f[2];
#pragma unroll
    for (int kt = 0; kt < 4; kt++)
        w1f[kt] = *(const short8*)(w1s + ((w * 4 + kt) * 64 + lane) * 8);
#pragma unroll
    for (int kt = 0; kt < 2; kt++)
        w2f[kt] = *(const short8*)(w2s + ((w * 2 + kt) * 64 + lane) * 8);
    const int col = w * 16 + l15;
    float b1v = b1[col];
    float b2v = b2[col];
    float wLv = w1last[col];   // W1 row 128 (e_val input), fp32

    for (int tile = blockIdx.x; tile < n_tiles; tile += gridDim.x) {
        // ---- gather (sorted payloads, coalesced/broadcast reads) ----
#pragma unroll
        for (int t = 0; t < 4; t++) {
            int e = e0 + t * 16;
            int ge = tile * 64 + e;
            int2 uv = se_uv[ge];
            const u16* src = (cch < 8)
                ? (u_feat + (size_t)uv.x * 64 + cch * 8)
                : (v_feat + (size_t)uv.y * 64 + (cch - 8) * 8);
            *(uint4*)(&A[e * 136 + cch * 8]) = *(const uint4*)src;
        }
        if (tid < 64) {
            Su[tid] = se_uv[tile * 64 + tid].x;
            Sev[tid] = se_ev[tile * 64 + tid];
        }
        __syncthreads();

        // ---- layer 1: 16 MFMAs + fp32 e_val term in epilogue ----
#pragma unroll
        for (int mt = 0; mt < 4; mt++) {
            f32x4 acc = {0.f, 0.f, 0.f, 0.f};
#pragma unroll
            for (int kt = 0; kt < 4; kt++) {
                short8 a = *(const short8*)(&A[(mt * 16 + l15) * 136 + kt * 32 + lq * 8]);
                acc = __builtin_amdgcn_mfma_f32_16x16x32_bf16(a, w1f[kt], acc, 0, 0, 0);
            }
#pragma unroll
            for (int r = 0; r < 4; r++) {
                int row = mt * 16 + lq * 4 + r;
                float hv = fmaxf(acc[r] + b1v + Sev[row] * wLv, 0.f);
                Hs[row * 72 + col] = bf16rne(hv);
            }
        }
        __syncthreads();

        // ---- layer 2: 8 MFMAs -> f32 Gs (aliases dead A) ----
#pragma unroll
        for (int mt = 0; mt < 4; mt++) {
            f32x4 acc = {0.f, 0.f, 0.f, 0.f};
#pragma unroll
            for (int kt = 0; kt < 2; kt++) {
                short8 a = *(const short8*)(&Hs[(mt * 16 + l15) * 72 + kt * 32 + lq * 8]);
                acc = __builtin_amdgcn_mfma_f32_16x16x32_bf16(a, w2f[kt], acc, 0, 0, 0);
            }
#pragma unroll
            for (int r = 0; r < 4; r++)
                Gs[(mt * 16 + lq * 4 + r) * 67 + col] = fmaxf(acc[r] + b2v, 0.f);
        }
        __syncthreads();

        // ---- segmented reduce: lane scans rows [16lq,16lq+16) for its col ----
        {
            int base = lq * 16;
            float partial = 0.f;
            int cur = Su[base];
#pragma unroll
            for (int s = 0; s < 16; s++) {
                partial += Gs[(base + s) * 67 + col];
                int nxt = (s == 15) ? -1 : Su[base + s + 1];
                if (nxt != cur) {
                    __hip_atomic_fetch_add(&agg[(size_t)cur * 64 + col], partial,
                                           __ATOMIC_RELAXED, __HIP_MEMORY_SCOPE_AGENT);
                    partial = 0.f;
                    cur = nxt;
                }
            }
        }
        __syncthreads();   // protect A/Gs/Su/Sev before next gather
    }
}

extern "C" void kernel_launch(void* const* d_in, const int* in_sizes, int n_in,
                              void* d_out, int out_size, void* d_ws, size_t ws_size,
                              hipStream_t stream) {
    const float* v        = (const float*)d_in[0];
    const float* c        = (const float*)d_in[1];
    const int*   cons_idx = (const int*)d_in[2];
    const int*   var_idx  = (const int*)d_in[3];
    const float* e_val    = (const float*)d_in[4];
    const float* ev_w1 = (const float*)d_in[5],  *ev_b1 = (const float*)d_in[6];
    const float* ev_w2 = (const float*)d_in[7],  *ev_b2 = (const float*)d_in[8];
    const float* ec_w1 = (const float*)d_in[9],  *ec_b1 = (const float*)d_in[10];
    const float* ec_w2 = (const float*)d_in[11], *ec_b2 = (const float*)d_in[12];
    const float* cg_w1 = (const float*)d_in[13], *cg_b1 = (const float*)d_in[14];
    const float* cg_w2 = (const float*)d_in[15], *cg_b2 = (const float*)d_in[16];
    const float* cf_w1 = (const float*)d_in[17], *cf_b1 = (const float*)d_in[18];
    const float* cf_w2 = (const float*)d_in[19], *cf_b2 = (const float*)d_in[20];
    const float* vg_w1 = (const float*)d_in[21], *vg_b1 = (const float*)d_in[22];
    const float* vg_w2 = (const float*)d_in[23], *vg_b2 = (const float*)d_in[24];
    const float* vf_w1 = (const float*)d_in[25], *vf_b1 = (const float*)d_in[26];
    const float* vf_w2 = (const float*)d_in[27], *vf_b2 = (const float*)d_in[28];
    const float* t_w1  = (const float*)d_in[29], *t_b1  = (const float*)d_in[30];
    const float* t_w2  = (const float*)d_in[31], *t_b2  = (const float*)d_in[32];

    const int NV = in_sizes[0] / 19;
    const int NC = in_sizes[1] / 5;
    const int NE = in_sizes[4];

    char* ws = (char*)d_ws;
    size_t off = 0;
    u16* v1bf = (u16*)(ws + off); off += (size_t)NV * 64 * 2;
    u16* c1bf = (u16*)(ws + off); off += (size_t)NC * 64 * 2;
    u16* c2bf = (u16*)(ws + off); off += (size_t)NC * 64 * 2;
    // agg_c and agg_v adjacent -> one memset
    float* agg_c = (float*)(ws + off); off += (size_t)NC * 64 * 4;
    float* agg_v = (float*)(ws + off); off += (size_t)NV * 64 * 4;
    u16* ev1s = (u16*)(ws + off); off += 2048 * 2;
    u16* ev2s = (u16*)(ws + off); off += 4096 * 2;
    u16* ec1s = (u16*)(ws + off); off += 2048 * 2;
    u16* ec2s = (u16*)(ws + off); off += 4096 * 2;
    u16* cg1s = (u16*)(ws + off); off += 8192 * 2;
    u16* cg2s = (u16*)(ws + off); off += 4096 * 2;
    u16* cf1s = (u16*)(ws + off); off += 8192 * 2;
    u16* cf2s = (u16*)(ws + off); off += 4096 * 2;
    u16* vg1s = (u16*)(ws + off); off += 8192 * 2;
    u16* vg2s = (u16*)(ws + off); off += 4096 * 2;
    u16* vf1s = (u16*)(ws + off); off += 8192 * 2;
    u16* vf2s = (u16*)(ws + off); off += 4096 * 2;
    u16* t1s  = (u16*)(ws + off); off += 4096 * 2;
    off = (off + 255) & ~(size_t)255;
    // cnt_c/cnt_v adjacent -> one memset
    u32* cnt_c  = (u32*)(ws + off); off += (size_t)NC * 4;
    u32* cnt_v  = (u32*)(ws + off); off += (size_t)NV * 4;
    u32* cur_c  = (u32*)(ws + off); off += (size_t)NC * 4;
    u32* cur_v  = (u32*)(ws + off); off += (size_t)NV * 4;
    u32* bsum_c = (u32*)(ws + off); off += 128 * 4;
    u32* bsum_v = (u32*)(ws + off); off += 128 * 4;
    off = (off + 255) & ~(size_t)255;
    int2*  se_c_uv = (int2*)(ws + off);  off += (size_t)NE * 8;
    float* se_c_ev = (float*)(ws + off); off += (size_t)NE * 4;
    int2*  se_v_uv = (int2*)(ws + off);  off += (size_t)NE * 8;
    float* se_v_ev = (float*)(ws + off); off += (size_t)NE * 4;

    const int nb_c = (NC + 1023) / 1024;
    const int nb_v = (NV + 1023) / 1024;
    const int nb_max = nb_c > nb_v ? nb_c : nb_v;

    // --- CSR build: 1 memset + 5 kernels ---
    hipMemsetAsync(cnt_c, 0, (size_t)(NC + NV) * 4, stream);
    hist_both<<<1024, 256, 0, stream>>>(cons_idx, var_idx, NE, cnt_c, cnt_v);
    scan_p1<<<dim3(nb_max, 2), 256, 0, stream>>>(cnt_c, NC, bsum_c, cnt_v, NV, bsum_v);
    scan_p2<<<dim3(1, 2), 128, 0, stream>>>(bsum_c, NC, bsum_v, NV);
    scan_p3<<<dim3(nb_max, 2), 256, 0, stream>>>(cnt_c, NC, bsum_c, cur_c,
                                                 cnt_v, NV, bsum_v, cur_v);
    scatter_both<<<1024, 256, 0, stream>>>(cons_idx, var_idx, e_val, NE,
                                           cur_c, cur_v, se_c_uv, se_c_ev,
                                           se_v_uv, se_v_ev);

    prep_weights<<<40, 256, 0, stream>>>(
        ev_w1, ev_w2, ec_w1, ec_w2, cg_w1, cg_w2, cf_w1, cf_w2,
        vg_w1, vg_w2, vf_w1, vf_w2, t_w1,
        ev1s, ev2s, ec1s, ec2s, cg1s, cg2s, cf1s, cf2s,
        vg1s, vg2s, vf1s, vf2s, t1s);

    node_mlp_in<19><<<(NV + 63) / 64, 256, 0, stream>>>(
        v, NV, ev1s, ev_b1, ev2s, ev_b2, v1bf);
    node_mlp_in<5><<<(NC + 63) / 64, 256, 0, stream>>>(
        c, NC, ec1s, ec_b1, ec2s, ec_b2, c1bf);

    hipMemsetAsync(agg_c, 0, (size_t)(NC + NV) * 64 * 4, stream);
    edge_conv<<<1536, 256, 0, stream>>>(c1bf, v1bf, se_c_uv, se_c_ev,
                                        cg1s, cg_w1 + 128 * 64, cg2s,
                                        cg_b1, cg_b2, agg_c, NE / 64);
    node_mlp_f<<<(NC + 63) / 64, 256, 0, stream>>>(
        c1bf, agg_c, NC, cf1s, cf_b1, cf2s, cf_b2, c2bf);

    edge_conv<<<1536, 256, 0, stream>>>(v1bf, c2bf, se_v_uv, se_v_ev,
                                        vg1s, vg_w1 + 128 * 64, vg2s,
                                        vg_b1, vg_b2, agg_v, NE / 64);
    node_mlp_vf_tail<<<(NV + 63) / 64, 256, 0, stream>>>(
        v1bf, agg_v, NV, vf1s, vf_b1, vf2s, vf_b2,
        t1s, t_b1, t_w2, t_b2, (float*)d_out);
}

// Round 8
// 650.859 us; speedup vs baseline: 1.2523x; 1.0263x over previous
//
#include <hip/hip_runtime.h>
#include <hip/hip_bf16.h>

typedef short short8 __attribute__((ext_vector_type(8)));
typedef float f32x4 __attribute__((ext_vector_type(4)));
typedef unsigned short u16;
typedef unsigned int u32;

__device__ __forceinline__ u16 bf16rne(float f) {
    u32 u = __float_as_uint(f);
    u32 r = (u + 0x7fffu + ((u >> 16) & 1u)) >> 16;
    return (u16)r;
}
__device__ __forceinline__ float bf2f(u16 s) {
    return __uint_as_float(((u32)s) << 16);
}

// ---------------------------------------------------------------------------
// Weight swizzle into MFMA B-fragment order, bf16 (K <= KT*32, zero-padded).
// ---------------------------------------------------------------------------
__device__ __forceinline__ void swz(const float* __restrict__ src,
                                    u16* __restrict__ dst, int K, int KT,
                                    int tid0, int stride) {
    int total = 4 * KT * 512;
    for (int i = tid0; i < total; i += stride) {
        int j = i & 7, lane = (i >> 3) & 63, g = i >> 9;
        int kt = g % KT;
        int k = kt * 32 + (lane >> 4) * 8 + j;
        int n = (g / KT) * 16 + (lane & 15);
        dst[i] = (k < K) ? bf16rne(src[k * 64 + n]) : (u16)0;
    }
}

__global__ void prep_weights(
    const float* ev1, const float* ev2, const float* ec1, const float* ec2,
    const float* cg1, const float* cg2, const float* cf1, const float* cf2,
    const float* vg1, const float* vg2, const float* vf1, const float* vf2,
    const float* t1,
    u16* dev1, u16* dev2, u16* dec1, u16* dec2, u16* dcg1, u16* dcg2,
    u16* dcf1, u16* dcf2, u16* dvg1, u16* dvg2, u16* dvf1, u16* dvf2,
    u16* dt1) {
    int tid0 = blockIdx.x * blockDim.x + threadIdx.x;
    int st = gridDim.x * blockDim.x;
    swz(ev1, dev1, 19, 1, tid0, st);
    swz(ev2, dev2, 64, 2, tid0, st);
    swz(ec1, dec1, 5, 1, tid0, st);
    swz(ec2, dec2, 64, 2, tid0, st);
    swz(cg1, dcg1, 128, 4, tid0, st);   // row 128 (e_val) handled in epilogue
    swz(cg2, dcg2, 64, 2, tid0, st);
    swz(cf1, dcf1, 128, 4, tid0, st);
    swz(cf2, dcf2, 64, 2, tid0, st);
    swz(vg1, dvg1, 128, 4, tid0, st);
    swz(vg2, dvg2, 64, 2, tid0, st);
    swz(vf1, dvf1, 128, 4, tid0, st);
    swz(vf2, dvf2, 64, 2, tid0, st);
    swz(t1, dt1, 64, 2, tid0, st);
}

// ---------------------------------------------------------------------------
// CSR build: hist both -> 2D scans (emit start + cur) -> XCD-partitioned
// scatter of sorted payloads (each output line written from one XCD).
// ---------------------------------------------------------------------------
__global__ void hist_both(const int* __restrict__ ci, const int* __restrict__ vi,
                          int ne, u32* __restrict__ cc, u32* __restrict__ cv) {
    for (int i = blockIdx.x * blockDim.x + threadIdx.x; i < ne;
         i += gridDim.x * blockDim.x) {
        atomicAdd(&cc[ci[i]], 1u);
        atomicAdd(&cv[vi[i]], 1u);
    }
}

__global__ __launch_bounds__(256) void scan_p1(
    const u32* __restrict__ c0, int n0, u32* __restrict__ bs0,
    const u32* __restrict__ c1, int n1, u32* __restrict__ bs1) {
    const u32* cnt = blockIdx.y ? c1 : c0;
    int n = blockIdx.y ? n1 : n0;
    u32* bsum = blockIdx.y ? bs1 : bs0;
    int nb = (n + 1023) / 1024;
    int b = blockIdx.x;
    if (b >= nb) return;
    __shared__ u32 sred[256];
    int t = threadIdx.x;
    int i0 = b * 1024 + t * 4;
    u32 s = 0;
#pragma unroll
    for (int j = 0; j < 4; j++) { int i = i0 + j; if (i < n) s += cnt[i]; }
    sred[t] = s;
    __syncthreads();
    for (int d = 128; d > 0; d >>= 1) {
        if (t < d) sred[t] += sred[t + d];
        __syncthreads();
    }
    if (t == 0) bsum[b] = sred[0];
}

__global__ __launch_bounds__(128) void scan_p2(u32* __restrict__ bs0, int n0,
                                               u32* __restrict__ bs1, int n1) {
    u32* bsum = blockIdx.y ? bs1 : bs0;
    int nb = ((blockIdx.y ? n1 : n0) + 1023) / 1024;
    __shared__ u32 sc[128];
    int t = threadIdx.x;
    u32 v = (t < nb) ? bsum[t] : 0;
    u32 mine = v;
    sc[t] = v;
    __syncthreads();
    for (int d = 1; d < 128; d <<= 1) {
        u32 a = (t >= d) ? sc[t - d] : 0;
        __syncthreads();
        sc[t] += a;
        __syncthreads();
    }
    if (t < nb) bsum[t] = sc[t] - mine;   // exclusive
}

__global__ __launch_bounds__(256) void scan_p3(
    const u32* __restrict__ c0, int n0, const u32* __restrict__ bs0,
    u32* __restrict__ st0, u32* __restrict__ cu0,
    const u32* __restrict__ c1, int n1, const u32* __restrict__ bs1,
    u32* __restrict__ st1, u32* __restrict__ cu1) {
    const u32* cnt = blockIdx.y ? c1 : c0;
    int n = blockIdx.y ? n1 : n0;
    const u32* bsum = blockIdx.y ? bs1 : bs0;
    u32* stt = blockIdx.y ? st1 : st0;
    u32* cur = blockIdx.y ? cu1 : cu0;
    int nb = (n + 1023) / 1024;
    int b = blockIdx.x;
    if (b >= nb) return;
    __shared__ u32 sc[256];
    int t = threadIdx.x;
    int i0 = b * 1024 + t * 4;
    u32 e[4];
    u32 s = 0;
#pragma unroll
    for (int j = 0; j < 4; j++) { int i = i0 + j; e[j] = (i < n) ? cnt[i] : 0; s += e[j]; }
    u32 mine = s;
    sc[t] = s;
    __syncthreads();
    for (int d = 1; d < 256; d <<= 1) {
        u32 a = (t >= d) ? sc[t - d] : 0;
        __syncthreads();
        sc[t] += a;
        __syncthreads();
    }
    u32 base = bsum[b] + sc[t] - mine;
#pragma unroll
    for (int j = 0; j < 4; j++) {
        int i = i0 + j;
        if (i < n) { stt[i] = base; cur[i] = base; base += e[j]; }
    }
}

// 8 position-range groups; blocks with blockIdx&7==g (XCD round-robin) handle
// group g. Each group scans all edges; writes only destinations whose start
// position falls in its range -> each payload cache line written by one XCD.
__global__ __launch_bounds__(256) void scatter_xcd(
    const int* __restrict__ ci, const int* __restrict__ vi,
    const float* __restrict__ ev, int ne,
    const u32* __restrict__ start_c, const u32* __restrict__ start_v,
    u32* __restrict__ cur_c, u32* __restrict__ cur_v,
    int2* __restrict__ se_c_uv, float* __restrict__ se_c_ev,
    int2* __restrict__ se_v_uv, float* __restrict__ se_v_ev) {
    int g = blockIdx.x & 7;
    int bb = blockIdx.x >> 3;
    int nb = gridDim.x >> 3;
    float inv = 8.0f / (float)ne;   // group(start) = floor(start*8/ne), consistent per node
    for (int i = bb * 256 + threadIdx.x; i < ne; i += nb * 256) {
        int cI = ci[i], vI = vi[i];
        float e = ev[i];
        int gc = (int)((float)start_c[cI] * inv);
        if (gc == g) {
            u32 p = atomicAdd(&cur_c[cI], 1u);
            se_c_uv[p] = make_int2(cI, vI);
            se_c_ev[p] = e;
        }
        int gv = (int)((float)start_v[vI] * inv);
        if (gv == g) {
            u32 p = atomicAdd(&cur_v[vI], 1u);
            se_v_uv[p] = make_int2(vI, cI);
            se_v_ev[p] = e;
        }
    }
}

// ---------------------------------------------------------------------------
// Generic MFMA layer for node MLPs (stride-72 bf16 out).
// ---------------------------------------------------------------------------
template <int KT, int SA>
__device__ __forceinline__ void mfma_layer(const u16* __restrict__ Asrc,
                                           const short8* wf, float bv,
                                           u16* __restrict__ Hdst,
                                           int l15, int lq, int w) {
#pragma unroll
    for (int mt = 0; mt < 4; mt++) {
        f32x4 acc = {0.f, 0.f, 0.f, 0.f};
#pragma unroll
        for (int kt = 0; kt < KT; kt++) {
            short8 a = *(const short8*)(Asrc + (mt * 16 + l15) * SA + kt * 32 + lq * 8);
            acc = __builtin_amdgcn_mfma_f32_16x16x32_bf16(a, wf[kt], acc, 0, 0, 0);
        }
#pragma unroll
        for (int r = 0; r < 4; r++)
            Hdst[(mt * 16 + lq * 4 + r) * 72 + w * 16 + l15] =
                bf16rne(fmaxf(acc[r] + bv, 0.f));
    }
}

// ---------------------------------------------------------------------------
// Input node MLP (MFMA): x[KIN] -> 64 -> 64, relu/relu, bf16 out.
// ---------------------------------------------------------------------------
template <int KIN>
__global__ __launch_bounds__(256, 4) void node_mlp_in(
    const float* __restrict__ x, int n_nodes,
    const u16* __restrict__ w1s, const float* __restrict__ b1,
    const u16* __restrict__ w2s, const float* __restrict__ b2,
    u16* __restrict__ outbf) {
    __shared__ __align__(16) u16 A[64 * 40];
    __shared__ __align__(16) u16 H1[64 * 72];
    __shared__ __align__(16) u16 H2[64 * 72];
    int tid = threadIdx.x, l = tid & 63, w = tid >> 6;
    int l15 = l & 15, lq = l >> 4;
    int blk0 = blockIdx.x * 64;
    const int PW = 40 - KIN;
    for (int i = tid; i < 64 * PW; i += 256) {
        int r = i / PW, cc = KIN + (i - r * PW);
        A[r * 40 + cc] = 0;
    }
    for (int i = tid; i < 64 * KIN; i += 256) {
        int r = i / KIN, k = i - r * KIN;
        int gn = blk0 + r; if (gn >= n_nodes) gn = n_nodes - 1;
        A[r * 40 + k] = bf16rne(x[(size_t)gn * KIN + k]);
    }
    short8 w1f[1], w2f[2];
    w1f[0] = *(const short8*)(w1s + ((w * 1 + 0) * 64 + l) * 8);
#pragma unroll
    for (int kt = 0; kt < 2; kt++)
        w2f[kt] = *(const short8*)(w2s + ((w * 2 + kt) * 64 + l) * 8);
    float b1v = b1[w * 16 + l15], b2v = b2[w * 16 + l15];
    __syncthreads();
    mfma_layer<1, 40>(A, w1f, b1v, H1, l15, lq, w);
    __syncthreads();
    mfma_layer<2, 72>(H1, w2f, b2v, H2, l15, lq, w);
    __syncthreads();
    for (int i = tid; i < 512; i += 256) {
        int r = i >> 3, c = i & 7;
        if (blk0 + r < n_nodes)
            *(uint4*)(outbf + (size_t)(blk0 + r) * 64 + c * 8) =
                *(const uint4*)(H2 + r * 72 + c * 8);
    }
}

// ---------------------------------------------------------------------------
// f-MLP staging: A[64 x 200] bf16 = [u(64) | agg_hi(64) | agg_res(64) | pad].
// ---------------------------------------------------------------------------
__device__ __forceinline__ void stage_concat_res(
    const u16* __restrict__ ubf, const float* __restrict__ agg,
    int blk0, int n_nodes, u16* __restrict__ A, int tid) {
    for (int i = tid; i < 64 * 24; i += 256) {
        int nd = i / 24, c = i - nd * 24;
        int gn = blk0 + nd; if (gn >= n_nodes) gn = n_nodes - 1;
        if (c < 8) {
            *(uint4*)(A + nd * 200 + c * 8) =
                *(const uint4*)(ubf + (size_t)gn * 64 + c * 8);
        } else {
            int q = c - 8;
            float4 av = *(const float4*)(agg + (size_t)gn * 64 + q * 4);
            u16 h0 = bf16rne(av.x), h1 = bf16rne(av.y);
            u16 h2 = bf16rne(av.z), h3 = bf16rne(av.w);
            uint2 hi;
            hi.x = (u32)h0 | ((u32)h1 << 16);
            hi.y = (u32)h2 | ((u32)h3 << 16);
            *(uint2*)(A + nd * 200 + 64 + q * 4) = hi;
            uint2 rs;
            rs.x = (u32)bf16rne(av.x - bf2f(h0)) | ((u32)bf16rne(av.y - bf2f(h1)) << 16);
            rs.y = (u32)bf16rne(av.z - bf2f(h2)) | ((u32)bf16rne(av.w - bf2f(h3)) << 16);
            *(uint2*)(A + nd * 200 + 128 + q * 4) = rs;
        }
    }
}

// ---------------------------------------------------------------------------
// c-side f-MLP (MFMA).
// ---------------------------------------------------------------------------
__global__ __launch_bounds__(256, 2) void node_mlp_f(
    const u16* __restrict__ ubf, const float* __restrict__ agg, int n_nodes,
    const u16* __restrict__ w1s, const float* __restrict__ b1,
    const u16* __restrict__ w2s, const float* __restrict__ b2,
    u16* __restrict__ outbf) {
    __shared__ __align__(16) u16 A[64 * 200];
    __shared__ __align__(16) u16 H1[64 * 72];
    int tid = threadIdx.x, l = tid & 63, w = tid >> 6;
    int l15 = l & 15, lq = l >> 4;
    int blk0 = blockIdx.x * 64;
    stage_concat_res(ubf, agg, blk0, n_nodes, A, tid);
    short8 w1f[6], w2f[2];
#pragma unroll
    for (int kt = 0; kt < 4; kt++)
        w1f[kt] = *(const short8*)(w1s + ((w * 4 + kt) * 64 + l) * 8);
    w1f[4] = w1f[2];
    w1f[5] = w1f[3];
#pragma unroll
    for (int kt = 0; kt < 2; kt++)
        w2f[kt] = *(const short8*)(w2s + ((w * 2 + kt) * 64 + l) * 8);
    float b1v = b1[w * 16 + l15], b2v = b2[w * 16 + l15];
    __syncthreads();
    mfma_layer<6, 200>(A, w1f, b1v, H1, l15, lq, w);
    __syncthreads();
    mfma_layer<2, 72>(H1, w2f, b2v, A, l15, lq, w);
    __syncthreads();
    for (int i = tid; i < 512; i += 256) {
        int r = i >> 3, c = i & 7;
        if (blk0 + r < n_nodes)
            *(uint4*)(outbf + (size_t)(blk0 + r) * 64 + c * 8) =
                *(const uint4*)(A + r * 72 + c * 8);
    }
}

// ---------------------------------------------------------------------------
// v-side f-MLP + tail (MFMA).
// ---------------------------------------------------------------------------
__global__ __launch_bounds__(256, 2) void node_mlp_vf_tail(
    const u16* __restrict__ vbf, const float* __restrict__ agg, int n_nodes,
    const u16* __restrict__ w1s, const float* __restrict__ b1,
    const u16* __restrict__ w2s, const float* __restrict__ b2,
    const u16* __restrict__ t1s, const float* __restrict__ tb1,
    const float* __restrict__ tw2, const float* __restrict__ tb2,
    float* __restrict__ out) {
    __shared__ __align__(16) char smem[64 * 200 * 2 + 2 * 64 * 72 * 2];
    u16* A = (u16*)smem;
    float* XF = (float*)smem;       // stride 65, reuses A region
    u16* H1 = (u16*)(smem + 25600);
    u16* H2 = (u16*)(smem + 25600 + 9216);
    int tid = threadIdx.x, l = tid & 63, w = tid >> 6;
    int l15 = l & 15, lq = l >> 4;
    int blk0 = blockIdx.x * 64;
    stage_concat_res(vbf, agg, blk0, n_nodes, A, tid);
    short8 w1f[6], w2f[2], t1f[2];
#pragma unroll
    for (int kt = 0; kt < 4; kt++)
        w1f[kt] = *(const short8*)(w1s + ((w * 4 + kt) * 64 + l) * 8);
    w1f[4] = w1f[2];
    w1f[5] = w1f[3];
#pragma unroll
    for (int kt = 0; kt < 2; kt++) {
        w2f[kt] = *(const short8*)(w2s + ((w * 2 + kt) * 64 + l) * 8);
        t1f[kt] = *(const short8*)(t1s + ((w * 2 + kt) * 64 + l) * 8);
    }
    float b1v = b1[w * 16 + l15], b2v = b2[w * 16 + l15];
    float tb1v = tb1[w * 16 + l15];
    __syncthreads();
    mfma_layer<6, 200>(A, w1f, b1v, H1, l15, lq, w);
    __syncthreads();
    mfma_layer<2, 72>(H1, w2f, b2v, H2, l15, lq, w);
    __syncthreads();
#pragma unroll
    for (int mt = 0; mt < 4; mt++) {
        f32x4 acc = {0.f, 0.f, 0.f, 0.f};
#pragma unroll
        for (int kt = 0; kt < 2; kt++) {
            short8 a = *(const short8*)(H2 + (mt * 16 + l15) * 72 + kt * 32 + lq * 8);
            acc = __builtin_amdgcn_mfma_f32_16x16x32_bf16(a, t1f[kt], acc, 0, 0, 0);
        }
#pragma unroll
        for (int r = 0; r < 4; r++)
            XF[(mt * 16 + lq * 4 + r) * 65 + w * 16 + l15] =
                fmaxf(acc[r] + tb1v, 0.f);
    }
    __syncthreads();
    float s0 = tb2[2 * w], s1 = tb2[2 * w + 1];
    for (int k = 0; k < 64; k++) {
        float xk = XF[l * 65 + k];
        float2 wp = *(const float2*)(tw2 + k * 8 + 2 * w);
        s0 = fmaf(xk, wp.x, s0);
        s1 = fmaf(xk, wp.y, s1);
    }
    if (blk0 + l < n_nodes) {
        float2 r;
        r.x = 1.f / (1.f + __expf(-s0));
        r.y = 1.f / (1.f + __expf(-s1));
        *(float2*)(out + (size_t)(blk0 + l) * 8 + 2 * w) = r;
    }
}

// ---------------------------------------------------------------------------
// Edge conv v3 (unchanged from R7): sorted payloads, e_val in L1 epilogue,
// Gs aliased onto dead A. LDS 26.5 KB -> 6 blocks/CU. 4 barriers/tile.
// ---------------------------------------------------------------------------
__global__ __launch_bounds__(256, 6) void edge_conv(
    const u16* __restrict__ u_feat, const u16* __restrict__ v_feat,
    const int2* __restrict__ se_uv, const float* __restrict__ se_ev,
    const u16* __restrict__ w1s, const float* __restrict__ w1last,
    const u16* __restrict__ w2s,
    const float* __restrict__ b1, const float* __restrict__ b2,
    float* __restrict__ agg, int n_tiles) {
    __shared__ __align__(16) char smem[27136];
    u16* A = (u16*)smem;                   // stride 136
    float* Gs = (float*)smem;              // stride 67, aliases A
    u16* Hs = (u16*)(smem + 17408);        // stride 72
    int* Su = (int*)(smem + 26624);
    float* Sev = (float*)(smem + 26880);

    int tid = threadIdx.x;
    int lane = tid & 63;
    int w = tid >> 6;
    int l15 = lane & 15, lq = lane >> 4;
    int cch = tid & 15, e0 = tid >> 4;

    short8 w1f[4], w2f[2];
#pragma unroll
    for (int kt = 0; kt < 4; kt++)
        w1f[kt] = *(const short8*)(w1s + ((w * 4 + kt) * 64 + lane) * 8);
#pragma unroll
    for (int kt = 0; kt < 2; kt++)
        w2f[kt] = *(const short8*)(w2s + ((w * 2 + kt) * 64 + lane) * 8);
    const int col = w * 16 + l15;
    float b1v = b1[col];
    float b2v = b2[col];
    float wLv = w1last[col];   // W1 row 128 (e_val input), fp32

    for (int tile = blockIdx.x; tile < n_tiles; tile += gridDim.x) {
        // ---- gather (sorted payloads, coalesced/broadcast reads) ----
#pragma unroll
        for (int t = 0; t < 4; t++) {
            int e = e0 + t * 16;
            int ge = tile * 64 + e;
            int2 uv = se_uv[ge];
            const u16* src = (cch < 8)
                ? (u_feat + (size_t)uv.x * 64 + cch * 8)
                : (v_feat + (size_t)uv.y * 64 + (cch - 8) * 8);
            *(uint4*)(&A[e * 136 + cch * 8]) = *(const uint4*)src;
        }
        if (tid < 64) {
            Su[tid] = se_uv[tile * 64 + tid].x;
            Sev[tid] = se_ev[tile * 64 + tid];
        }
        __syncthreads();

        // ---- layer 1: 16 MFMAs + fp32 e_val term in epilogue ----
#pragma unroll
        for (int mt = 0; mt < 4; mt++) {
            f32x4 acc = {0.f, 0.f, 0.f, 0.f};
#pragma unroll
            for (int kt = 0; kt < 4; kt++) {
                short8 a = *(const short8*)(&A[(mt * 16 + l15) * 136 + kt * 32 + lq * 8]);
                acc = __builtin_amdgcn_mfma_f32_16x16x32_bf16(a, w1f[kt], acc, 0, 0, 0);
            }
#pragma unroll
            for (int r = 0; r < 4; r++) {
                int row = mt * 16 + lq * 4 + r;
                float hv = fmaxf(acc[r] + b1v + Sev[row] * wLv, 0.f);
                Hs[row * 72 + col] = bf16rne(hv);
            }
        }
        __syncthreads();

        // ---- layer 2: 8 MFMAs -> f32 Gs (aliases dead A) ----
#pragma unroll
        for (int mt = 0; mt < 4; mt++) {
            f32x4 acc = {0.f, 0.f, 0.f, 0.f};
#pragma unroll
            for (int kt = 0; kt < 2; kt++) {
                short8 a = *(const short8*)(&Hs[(mt * 16 + l15) * 72 + kt * 32 + lq * 8]);
                acc = __builtin_amdgcn_mfma_f32_16x16x32_bf16(a, w2f[kt], acc, 0, 0, 0);
            }
#pragma unroll
            for (int r = 0; r < 4; r++)
                Gs[(mt * 16 + lq * 4 + r) * 67 + col] = fmaxf(acc[r] + b2v, 0.f);
        }
        __syncthreads();

        // ---- segmented reduce: lane scans rows [16lq,16lq+16) for its col ----
        {
            int base = lq * 16;
            float partial = 0.f;
            int cur = Su[base];
#pragma unroll
            for (int s = 0; s < 16; s++) {
                partial += Gs[(base + s) * 67 + col];
                int nxt = (s == 15) ? -1 : Su[base + s + 1];
                if (nxt != cur) {
                    __hip_atomic_fetch_add(&agg[(size_t)cur * 64 + col], partial,
                                           __ATOMIC_RELAXED, __HIP_MEMORY_SCOPE_AGENT);
                    partial = 0.f;
                    cur = nxt;
                }
            }
        }
        __syncthreads();   // protect A/Gs/Su/Sev before next gather
    }
}

extern "C" void kernel_launch(void* const* d_in, const int* in_sizes, int n_in,
                              void* d_out, int out_size, void* d_ws, size_t ws_size,
                              hipStream_t stream) {
    const float* v        = (const float*)d_in[0];
    const float* c        = (const float*)d_in[1];
    const int*   cons_idx = (const int*)d_in[2];
    const int*   var_idx  = (const int*)d_in[3];
    const float* e_val    = (const float*)d_in[4];
    const float* ev_w1 = (const float*)d_in[5],  *ev_b1 = (const float*)d_in[6];
    const float* ev_w2 = (const float*)d_in[7],  *ev_b2 = (const float*)d_in[8];
    const float* ec_w1 = (const float*)d_in[9],  *ec_b1 = (const float*)d_in[10];
    const float* ec_w2 = (const float*)d_in[11], *ec_b2 = (const float*)d_in[12];
    const float* cg_w1 = (const float*)d_in[13], *cg_b1 = (const float*)d_in[14];
    const float* cg_w2 = (const float*)d_in[15], *cg_b2 = (const float*)d_in[16];
    const float* cf_w1 = (const float*)d_in[17], *cf_b1 = (const float*)d_in[18];
    const float* cf_w2 = (const float*)d_in[19], *cf_b2 = (const float*)d_in[20];
    const float* vg_w1 = (const float*)d_in[21], *vg_b1 = (const float*)d_in[22];
    const float* vg_w2 = (const float*)d_in[23], *vg_b2 = (const float*)d_in[24];
    const float* vf_w1 = (const float*)d_in[25], *vf_b1 = (const float*)d_in[26];
    const float* vf_w2 = (const float*)d_in[27], *vf_b2 = (const float*)d_in[28];
    const float* t_w1  = (const float*)d_in[29], *t_b1  = (const float*)d_in[30];
    const float* t_w2  = (const float*)d_in[31], *t_b2  = (const float*)d_in[32];

    const int NV = in_sizes[0] / 19;
    const int NC = in_sizes[1] / 5;
    const int NE = in_sizes[4];

    char* ws = (char*)d_ws;
    size_t off = 0;
    u16* v1bf = (u16*)(ws + off); off += (size_t)NV * 64 * 2;
    u16* c1bf = (u16*)(ws + off); off += (size_t)NC * 64 * 2;
    u16* c2bf = (u16*)(ws + off); off += (size_t)NC * 64 * 2;
    // agg_c and agg_v adjacent -> one memset
    float* agg_c = (float*)(ws + off); off += (size_t)NC * 64 * 4;
    float* agg_v = (float*)(ws + off); off += (size_t)NV * 64 * 4;
    u16* ev1s = (u16*)(ws + off); off += 2048 * 2;
    u16* ev2s = (u16*)(ws + off); off += 4096 * 2;
    u16* ec1s = (u16*)(ws + off); off += 2048 * 2;
    u16* ec2s = (u16*)(ws + off); off += 4096 * 2;
    u16* cg1s = (u16*)(ws + off); off += 8192 * 2;
    u16* cg2s = (u16*)(ws + off); off += 4096 * 2;
    u16* cf1s = (u16*)(ws + off); off += 8192 * 2;
    u16* cf2s = (u16*)(ws + off); off += 4096 * 2;
    u16* vg1s = (u16*)(ws + off); off += 8192 * 2;
    u16* vg2s = (u16*)(ws + off); off += 4096 * 2;
    u16* vf1s = (u16*)(ws + off); off += 8192 * 2;
    u16* vf2s = (u16*)(ws + off); off += 4096 * 2;
    u16* t1s  = (u16*)(ws + off); off += 4096 * 2;
    off = (off + 255) & ~(size_t)255;
    // cnt_c/cnt_v adjacent -> one memset
    u32* cnt_c   = (u32*)(ws + off); off += (size_t)NC * 4;
    u32* cnt_v   = (u32*)(ws + off); off += (size_t)NV * 4;
    u32* start_c = (u32*)(ws + off); off += (size_t)NC * 4;
    u32* start_v = (u32*)(ws + off); off += (size_t)NV * 4;
    u32* cur_c   = (u32*)(ws + off); off += (size_t)NC * 4;
    u32* cur_v   = (u32*)(ws + off); off += (size_t)NV * 4;
    u32* bsum_c  = (u32*)(ws + off); off += 128 * 4;
    u32* bsum_v  = (u32*)(ws + off); off += 128 * 4;
    off = (off + 255) & ~(size_t)255;
    int2*  se_c_uv = (int2*)(ws + off);  off += (size_t)NE * 8;
    float* se_c_ev = (float*)(ws + off); off += (size_t)NE * 4;
    int2*  se_v_uv = (int2*)(ws + off);  off += (size_t)NE * 8;
    float* se_v_ev = (float*)(ws + off); off += (size_t)NE * 4;

    const int nb_c = (NC + 1023) / 1024;
    const int nb_v = (NV + 1023) / 1024;
    const int nb_max = nb_c > nb_v ? nb_c : nb_v;

    // --- CSR build: 1 memset + 5 kernels; scatter is XCD-partitioned ---
    hipMemsetAsync(cnt_c, 0, (size_t)(NC + NV) * 4, stream);
    hist_both<<<1024, 256, 0, stream>>>(cons_idx, var_idx, NE, cnt_c, cnt_v);
    scan_p1<<<dim3(nb_max, 2), 256, 0, stream>>>(cnt_c, NC, bsum_c, cnt_v, NV, bsum_v);
    scan_p2<<<dim3(1, 2), 128, 0, stream>>>(bsum_c, NC, bsum_v, NV);
    scan_p3<<<dim3(nb_max, 2), 256, 0, stream>>>(cnt_c, NC, bsum_c, start_c, cur_c,
                                                 cnt_v, NV, bsum_v, start_v, cur_v);
    scatter_xcd<<<960, 256, 0, stream>>>(cons_idx, var_idx, e_val, NE,
                                         start_c, start_v, cur_c, cur_v,
                                         se_c_uv, se_c_ev, se_v_uv, se_v_ev);

    prep_weights<<<40, 256, 0, stream>>>(
        ev_w1, ev_w2, ec_w1, ec_w2, cg_w1, cg_w2, cf_w1, cf_w2,
        vg_w1, vg_w2, vf_w1, vf_w2, t_w1,
        ev1s, ev2s, ec1s, ec2s, cg1s, cg2s, cf1s, cf2s,
        vg1s, vg2s, vf1s, vf2s, t1s);

    node_mlp_in<19><<<(NV + 63) / 64, 256, 0, stream>>>(
        v, NV, ev1s, ev_b1, ev2s, ev_b2, v1bf);
    node_mlp_in<5><<<(NC + 63) / 64, 256, 0, stream>>>(
        c, NC, ec1s, ec_b1, ec2s, ec_b2, c1bf);

    hipMemsetAsync(agg_c, 0, (size_t)(NC + NV) * 64 * 4, stream);
    edge_conv<<<1536, 256, 0, stream>>>(c1bf, v1bf, se_c_uv, se_c_ev,
                                        cg1s, cg_w1 + 128 * 64, cg2s,
                                        cg_b1, cg_b2, agg_c, NE / 64);
    node_mlp_f<<<(NC + 63) / 64, 256, 0, stream>>>(
        c1bf, agg_c, NC, cf1s, cf_b1, cf2s, cf_b2, c2bf);

    edge_conv<<<1536, 256, 0, stream>>>(v1bf, c2bf, se_v_uv, se_v_ev,
                                        vg1s, vg_w1 + 128 * 64, vg2s,
                                        vg_b1, vg_b2, agg_v, NE / 64);
    node_mlp_vf_tail<<<(NV + 63) / 64, 256, 0, stream>>>(
        v1bf, agg_v, NV, vf1s, vf_b1, vf2s, vf_b2,
        t1s, t_b1, t_w2, t_b2, (float*)d_out);
}